// Round 17
// baseline (51.338 us; speedup 1.0000x reference)
//
#include <hip/hip_runtime.h>
#include <math.h>

// F0Resonance — bit-exact replication of XLA's tiled-scan cumsum (r6..r16).
// phase(j) = fl(A0[j&15] + P1((j>>4)-1)), P1(m)=fl(B1[m&15]+fl(B2[..]+B3[..]))
// contract(off) REQUIRED (r7). Validated absmax = 1 bf16 quantum.
//
// r16->r17 perf: per-eval v_sin (est. 16-24cy on the trans pipe = ~half the
// issue budget) is ELIMINATED. sin(p) for p = fl(a0+c) is computed by angle
// addition: Fast2Sum gives e' = (p-c)-a0 EXACTLY (valid: c >= T0 >= a0);
// sin(p) = sin((a0+c)+e') ~= t1 + e'*t2, t1=sin(a0+c), t2=cos(a0+c) from
// per-block LDS tables of sin/cos(A0[k][i]) (256) and sin/cos(carry[k][lm])
// (2048), built once with CW-reduced hw v_sin/v_cos. Residual error
// e'^2/2 <= 1.2e-4 << bf16 quantum. Inner loop: 9 regular VALU, 0 trans.
#pragma clang fp contract(off)

constexpr int NSAMP = 32768;
constexpr int NROWS = 256;   // B*E = 4*64
constexpr int NOCT  = 16;
constexpr int SEGS  = 16;    // blocks per row (2048 samples each)
constexpr int TPB   = 256;
constexpr int GRID  = NROWS * SEGS;   // 4096

// hard barrier against cross-statement fusion on the scalar chain
__device__ __forceinline__ float keepf(float x) {
  asm volatile("" : "+v"(x));
  return x;
}

__device__ __forceinline__ float hwsin(float fr) {
  float s; asm("v_sin_f32 %0, %1" : "=v"(s) : "v"(fr)); return s;
}
__device__ __forceinline__ float hwcos(float fr) {
  float c; asm("v_cos_f32 %0, %1" : "=v"(c) : "v"(fr)); return c;
}

__global__ __launch_bounds__(TPB, 6) void f0res_k1(
    const float* __restrict__ f0_in,
    const float* __restrict__ dec_in,
    const float* __restrict__ fs_in,
    float* __restrict__ out,
    float* __restrict__ segmax)
{
  const int bid = blockIdx.x;
  const int row = bid >> 4;
  const int seg = bid & 15;
  const int t   = threadIdx.x;

  __shared__ float s_tab[NOCT][64];   // A0 | B1 | B2 | B3 tables
  __shared__ float s_w[NOCT];
  __shared__ float s_carr[NOCT][128]; // carry values P1(m)
  __shared__ float s_cc[NOCT][128];   // cos(carry)
  __shared__ float s_sc[NOCT][128];   // sin(carry)
  __shared__ float s_sa[NOCT][16];    // sin(A0)
  __shared__ float s_ca[NOCT][16];    // cos(A0)
  __shared__ float s_red[TPB / 64];

  // split 1/(2pi) for CW reduction (r15-validated: arg err ~2e-7 rad)
  const double INV2PI_D = 0.15915494309189533577;
  const float I1 = (float)INV2PI_D;
  const float I2 = (float)(INV2PI_D - (double)I1);

  // ---- fp32 scalar chain (reference roundings; contraction pinned off) ----
  const float f0a = fabsf(f0_in[row]);
  const float dcc = dec_in[row];
  const float fsv = fs_in[row];

  const float MIN_F = (float)(20.0 / 11025.0);
  const float RNG_F = (float)(3000.0 / 11025.0 - 20.0 / 11025.0);
  const float c1s   = keepf(f0a * RNG_F);       // fl32 mul
  const float c2s   = keepf(MIN_F + c1s);       // fl32 add (NOT fma)
  const float f0ang = keepf(c2s * (float)M_PI); // fl32 mul

  const float sg    = 1.0f / (1.0f + expf(-dcc));
  const float dvv   = 1.0f / (1.0f + expf(-sg));   // double sigmoid
  const float dvr   = keepf(dvv * 0.9405f);        // (1-0.01)*0.95
  const float decay = keepf(0.01f + dvr);          // fl32 add (NOT fma)
  const float ldv   = logf(decay + 1e-12f);

  // ---- builder 1: lane k builds octave k's scan tables + weight ----
  if (t < NOCT) {
    const int k = t;
    float fac = 0.0f;
    for (int j = 0; j <= k; ++j) fac = fac + fsv;   // 16-elem seq cumsum
    const float x = keepf(f0ang * fac);
    float* tab = s_tab[k];
    float a = 0.0f;
#pragma unroll
    for (int i = 0; i < 16; ++i) { a = a + x;  tab[i]      = a; }
    const float T0 = a; a = 0.0f;
#pragma unroll
    for (int i = 0; i < 16; ++i) { a = a + T0; tab[16 + i] = a; }
    const float T1 = a; a = 0.0f;
#pragma unroll
    for (int i = 0; i < 16; ++i) { a = a + T1; tab[32 + i] = a; }
    const float T2 = a; a = 0.0f;
#pragma unroll
    for (int i = 0; i < 8;  ++i) { a = a + T2; tab[48 + i] = a; }
    float lc = 0.0f;
    for (int j = 0; j <= k; ++j) lc = lc + ldv;     // seq cumsum of log_decay
    s_w[k] = expf(lc);
  }
  __syncthreads();

  // ---- builder 2: carries + their sin/cos; sin/cos of A0 ----
#pragma unroll
  for (int i = 0; i < (NOCT * 128) / TPB; ++i) {
    const int idx = t + i * TPB;      // 0..2047
    const int k   = idx >> 7;
    const int lm  = idx & 127;
    const int m   = (seg << 7) + lm - 1;
    const float* tab = s_tab[k];
    float c = 0.0f;
    if (m >= 0) {
      c = tab[16 + (m & 15)];         // SAME fp32 add order as reference
      const int m2 = (m >> 4) - 1;
      if (m2 >= 0) {
        float p2 = tab[32 + (m2 & 15)];
        const int m3 = (m2 >> 4) - 1;
        if (m3 >= 0) p2 = p2 + tab[48 + m3];
        c = c + p2;
      }
    }
    s_carr[k][lm] = c;
    const float kq = rintf(c * I1);
    float fr = __builtin_fmaf(c, I1, -kq);
    fr = __builtin_fmaf(c, I2, fr);
    s_sc[k][lm] = hwsin(fr);
    s_cc[k][lm] = hwcos(fr);
  }
  {
    const int k = t >> 4, i = t & 15;     // 256 entries, one per thread
    const float a0 = s_tab[k][i];
    const float kq = rintf(a0 * I1);
    float fr = __builtin_fmaf(a0, I1, -kq);
    fr = __builtin_fmaf(a0, I2, fr);
    s_sa[k][i] = hwsin(fr);
    s_ca[k][i] = hwcos(fr);
  }
  __syncthreads();

  // thread t owns samples j = 8u .. 8u+7, u = seg*256+t (half a scan window)
  const int lm = t >> 1;              // carry index
  const int a0base = (t & 1) * 2;     // float4 index into 16-entry A0 tables

  float osc[8];
#pragma unroll
  for (int e = 0; e < 8; ++e) osc[e] = 0.0f;

#pragma unroll 2
  for (int k = 0; k < NOCT; ++k) {
    const float carry = s_carr[k][lm];
    const float cC    = s_cc[k][lm];
    const float sC    = s_sc[k][lm];
    const float w     = s_w[k];

    float tv[8], sa[8], ca[8];
    *(float4*)&tv[0] = ((const float4*)s_tab[k])[a0base];
    *(float4*)&tv[4] = ((const float4*)s_tab[k])[a0base + 1];
    *(float4*)&sa[0] = ((const float4*)s_sa[k])[a0base & 3 ? a0base : a0base];  // same idx
    *(float4*)&sa[4] = ((const float4*)s_sa[k])[a0base + 1];
    *(float4*)&ca[0] = ((const float4*)s_ca[k])[a0base];
    *(float4*)&ca[4] = ((const float4*)s_ca[k])[a0base + 1];
    // fix first sa load (written plainly for clarity)
    *(float4*)&sa[0] = ((const float4*)s_sa[k])[a0base];

#pragma unroll
    for (int e = 0; e < 8; ++e) {
      const float p  = tv[e] + carry;     // exact reference phase bits
      const float z  = p - carry;         // Fast2Sum: exact (carry >= a0)
      const float ep = z - tv[e];         // e' = p - (a0+carry), exact
      float t1 = sa[e] * cC;
      t1 = __builtin_fmaf(ca[e], sC, t1);           // sin(a0+carry)
      float t2 = ca[e] * cC;
      t2 = __builtin_fmaf(-sa[e], sC, t2);          // cos(a0+carry)
      const float sv = __builtin_fmaf(ep, t2, t1);  // sin(p) + O(e'^2/2)
      osc[e] = __builtin_fmaf(w, sv, osc[e]);
    }
  }

  // ---- block |max| reduction -> plain store (no init, no atomic) ----
  float lmax = 0.0f;
#pragma unroll
  for (int e = 0; e < 8; ++e) lmax = fmaxf(lmax, fabsf(osc[e]));
#pragma unroll
  for (int off = 32; off >= 1; off >>= 1)
    lmax = fmaxf(lmax, __shfl_xor(lmax, off, 64));
  if ((t & 63) == 0) s_red[t >> 6] = lmax;
  __syncthreads();
  if (t == 0) {
    float mx = s_red[0];
#pragma unroll
    for (int i = 1; i < TPB / 64; ++i) mx = fmaxf(mx, s_red[i]);
    segmax[bid] = mx;
  }

  // ---- raw store, block-local PERMUTED layout (lane-contiguous) ----
  float4* o4 = (float4*)out + (size_t)bid * 512;
#pragma unroll
  for (int q = 0; q < 2; ++q) {
    float4 v;
    v.x = osc[4 * q + 0];
    v.y = osc[4 * q + 1];
    v.z = osc[4 * q + 2];
    v.w = osc[4 * q + 3];
    o4[q * 256 + t] = v;
  }
}

__global__ __launch_bounds__(TPB, 8) void f0res_k2(
    float* __restrict__ out,
    const float* __restrict__ segmax)
{
  const int bid = blockIdx.x;
  const int t   = threadIdx.x;
  const int row = bid >> 4;

  float mx = 0.0f;
#pragma unroll
  for (int i = 0; i < SEGS; ++i) mx = fmaxf(mx, segmax[row * SEGS + i]);
  const float inv = 1.0f / (mx + 1e-8f);

  float4* base = (float4*)out + (size_t)bid * 512;

  // gather: logical f4 l = q*256+t lives at raw slot (t&1)*256+q*128+(t>>1)
  float4 v[2];
#pragma unroll
  for (int q = 0; q < 2; ++q) {
    const int s = (t & 1) * 256 + q * 128 + (t >> 1);
    v[q] = base[s];
  }
  __syncthreads();   // vmcnt(0) drain: all reads precede writes (in-place ok)
#pragma unroll
  for (int q = 0; q < 2; ++q) {
    float4 x = v[q];
    x.x *= inv; x.y *= inv; x.z *= inv; x.w *= inv;
    base[q * 256 + t] = x;   // linear, lane-contiguous
  }
}

extern "C" void kernel_launch(void* const* d_in, const int* in_sizes, int n_in,
                              void* d_out, int out_size, void* d_ws, size_t ws_size,
                              hipStream_t stream) {
    const float* f0  = (const float*)d_in[0];  // (4,64,1)
    const float* dcc = (const float*)d_in[1];  // decay_coefficients
    // d_in[2] = phase_offsets: computed-but-unused in the reference
    const float* fsp = (const float*)d_in[3];  // freq_spacing
    float* out = (float*)d_out;                // (4,64,32768) fp32
    float* segmax = (float*)d_ws;              // 4096 floats, fully written/call

    f0res_k1<<<GRID, TPB, 0, stream>>>(f0, dcc, fsp, out, segmax);
    f0res_k2<<<GRID, TPB, 0, stream>>>(out, segmax);
}